// Round 5
// baseline (26.347 us; speedup 1.0000x reference)
//
#include <hip/hip_runtime.h>
#include <hip/hip_bf16.h>

constexpr int BATCH = 256;
constexpr int NREL  = 16;
constexpr int DIM   = 64;
constexpr int NHOP  = 2;
constexpr int NMEM  = 32;

// One 64-lane wave per (hop,b,r) triple.
//   sub = lane>>4 : one of 4 entity rows per float4 gather instruction
//   q   = lane&15 : float4 slot within the 256 B row
// R5 changes vs R4:
//   - all 96 memory indices loaded as SCALAR (SGPR) loads; per-sub select
//     via 2 v_cndmask (pick4) instead of ds_bpermute
//   - two rotating 4xfloat4 buffers (A,B): h0-3/h4-7 then reuse for t0-3/t4-7
//     -> peak 8 float4 live (32 VGPR) while 8 gathers always in flight
//   - target <=~70 VGPR -> 7-8 waves/SIMD occupancy for random-gather MLP
__device__ __forceinline__ int pick4(int s0, int s1, int s2, int s3, int sub) {
    const int ab = (sub & 1) ? s1 : s0;
    const int cd = (sub & 1) ? s3 : s2;
    return (sub & 2) ? cd : ab;
}

__global__ __launch_bounds__(256)
void kgan_kernel(const float* __restrict__ ent,      // [N_ENT+1, 64]
                 const float* __restrict__ rel,      // [16, 64]
                 const int*   __restrict__ items,    // [256]
                 const int*   __restrict__ mh,
                 const int*   __restrict__ mr,
                 const int*   __restrict__ mt,
                 float*       __restrict__ out)      // [2,256,16,64]
{
    __shared__ float rel_lds[NREL * DIM];            // 4 KB
    reinterpret_cast<float4*>(rel_lds)[threadIdx.x] =
        reinterpret_cast<const float4*>(rel)[threadIdx.x];
    __syncthreads();   // before any entity gathers -> barrier drain is cheap

    const int gtid = blockIdx.x * blockDim.x + threadIdx.x;
    const int lane = threadIdx.x & 63;
    const int sub  = lane >> 4;
    const int q    = lane & 15;
    // wave id is uniform across the 64 lanes -> make it provably scalar
    const int wave = __builtin_amdgcn_readfirstlane(gtid >> 6);
    const int b    = (wave >> 4) & (BATCH - 1);

    const float4* ent4 = reinterpret_cast<const float4*>(ent);
    const float4* rl4  = reinterpret_cast<const float4*>(rel_lds);

    // item embedding slice (scalar index -> s_load; gather varies only by q)
    const int item = items[b];
    const float4 v4 = ent4[(size_t)item * 16 + q];

    const int* mhw = mh + wave * NMEM;   // wave-uniform base -> scalar loads
    const int* mrw = mr + wave * NMEM;
    const int* mtw = mt + wave * NMEM;

    // ---- phase 1: issue all 8 h-row gathers (A: h0-3, B: h4-7) ----
    int sh[NMEM];
    #pragma unroll
    for (int k = 0; k < NMEM; ++k) sh[k] = mhw[k];

    auto gp = [&](int i0, int i1, int i2, int i3) -> const float4* {
        const int idx = pick4(i0, i1, i2, i3, sub);
        return ent4 + ((size_t)idx * 16 + q);
    };

    float4 A0 = *gp(sh[0],  sh[1],  sh[2],  sh[3]);
    float4 A1 = *gp(sh[4],  sh[5],  sh[6],  sh[7]);
    float4 A2 = *gp(sh[8],  sh[9],  sh[10], sh[11]);
    float4 A3 = *gp(sh[12], sh[13], sh[14], sh[15]);
    float4 B0 = *gp(sh[16], sh[17], sh[18], sh[19]);
    float4 B1 = *gp(sh[20], sh[21], sh[22], sh[23]);
    float4 B2 = *gp(sh[24], sh[25], sh[26], sh[27]);
    float4 B3 = *gp(sh[28], sh[29], sh[30], sh[31]);

    int sr[NMEM];
    #pragma unroll
    for (int k = 0; k < NMEM; ++k) sr[k] = mrw[k];

    float sc[8];
    auto score = [&](const float4& h4, int j) -> float {
        const int rj = pick4(sr[4*j], sr[4*j+1], sr[4*j+2], sr[4*j+3], sub);
        const float4 r4 = rl4[rj * 16 + q];
        float p = h4.x * r4.x * v4.x;
        p = fmaf(h4.y * r4.y, v4.y, p);
        p = fmaf(h4.z * r4.z, v4.z, p);
        p = fmaf(h4.w * r4.w, v4.w, p);
        p += __shfl_xor(p, 8, 64);
        p += __shfl_xor(p, 4, 64);
        p += __shfl_xor(p, 2, 64);
        p += __shfl_xor(p, 1, 64);
        return p;                      // score(4j+sub), replicated over q
    };

    // ---- phase 2: score A, refill A with t0-3 ----
    sc[0] = score(A0, 0);
    sc[1] = score(A1, 1);
    sc[2] = score(A2, 2);
    sc[3] = score(A3, 3);

    int st0[16];
    #pragma unroll
    for (int k = 0; k < 16; ++k) st0[k] = mtw[k];
    A0 = *gp(st0[0],  st0[1],  st0[2],  st0[3]);
    A1 = *gp(st0[4],  st0[5],  st0[6],  st0[7]);
    A2 = *gp(st0[8],  st0[9],  st0[10], st0[11]);
    A3 = *gp(st0[12], st0[13], st0[14], st0[15]);

    // ---- phase 3: score B, refill B with t4-7 ----
    sc[4] = score(B0, 4);
    sc[5] = score(B1, 5);
    sc[6] = score(B2, 6);
    sc[7] = score(B3, 7);

    int st1[16];
    #pragma unroll
    for (int k = 0; k < 16; ++k) st1[k] = mtw[16 + k];
    B0 = *gp(st1[0],  st1[1],  st1[2],  st1[3]);
    B1 = *gp(st1[4],  st1[5],  st1[6],  st1[7]);
    B2 = *gp(st1[8],  st1[9],  st1[10], st1[11]);
    B3 = *gp(st1[12], st1[13], st1[14], st1[15]);

    // ---- softmax over 32 memories (t gathers in flight underneath) ----
    float mx = sc[0];
    #pragma unroll
    for (int j = 1; j < 8; ++j) mx = fmaxf(mx, sc[j]);
    mx = fmaxf(mx, __shfl_xor(mx, 16, 64));
    mx = fmaxf(mx, __shfl_xor(mx, 32, 64));

    float sum = 0.f;
    #pragma unroll
    for (int j = 0; j < 8; ++j) {
        sc[j] = __expf(sc[j] - mx);
        sum += sc[j];
    }
    sum += __shfl_xor(sum, 16, 64);
    sum += __shfl_xor(sum, 32, 64);
    const float inv = 1.f / sum;

    // ---- PV ----
    float4 acc = make_float4(0.f, 0.f, 0.f, 0.f);
    auto pv = [&](const float4& t4, float p) {
        acc.x = fmaf(p, t4.x, acc.x);
        acc.y = fmaf(p, t4.y, acc.y);
        acc.z = fmaf(p, t4.z, acc.z);
        acc.w = fmaf(p, t4.w, acc.w);
    };
    pv(A0, sc[0] * inv);
    pv(A1, sc[1] * inv);
    pv(A2, sc[2] * inv);
    pv(A3, sc[3] * inv);
    pv(B0, sc[4] * inv);
    pv(B1, sc[5] * inv);
    pv(B2, sc[6] * inv);
    pv(B3, sc[7] * inv);

    acc.x += __shfl_xor(acc.x, 16, 64);
    acc.y += __shfl_xor(acc.y, 16, 64);
    acc.z += __shfl_xor(acc.z, 16, 64);
    acc.w += __shfl_xor(acc.w, 16, 64);
    acc.x += __shfl_xor(acc.x, 32, 64);
    acc.y += __shfl_xor(acc.y, 32, 64);
    acc.z += __shfl_xor(acc.z, 32, 64);
    acc.w += __shfl_xor(acc.w, 32, 64);

    if (sub == 0)
        reinterpret_cast<float4*>(out)[(size_t)wave * 16 + q] = acc;
}

extern "C" void kernel_launch(void* const* d_in, const int* in_sizes, int n_in,
                              void* d_out, int out_size, void* d_ws, size_t ws_size,
                              hipStream_t stream) {
    const float* ent   = (const float*)d_in[0];
    const float* rel   = (const float*)d_in[1];
    const int*   items = (const int*)d_in[2];
    const int*   mh    = (const int*)d_in[3];
    const int*   mr    = (const int*)d_in[4];
    const int*   mt    = (const int*)d_in[5];
    float* out = (float*)d_out;

    const int total_waves = NHOP * BATCH * NREL;     // 8192
    const int threads = 256;
    const int blocks = total_waves * 64 / threads;   // 2048

    kgan_kernel<<<blocks, threads, 0, stream>>>(ent, rel, items, mh, mr, mt, out);
}

// Round 6
// 26.015 us; speedup vs baseline: 1.0128x; 1.0128x over previous
//
#include <hip/hip_runtime.h>
#include <hip/hip_bf16.h>

constexpr int BATCH = 256;
constexpr int NREL  = 16;
constexpr int DIM   = 64;
constexpr int NHOP  = 2;
constexpr int NMEM  = 32;

// R6: TWO waves per (hop,b,r) triple, 16 memories each.
//   sub = lane>>4 : one of 4 entity rows per float4 gather instruction
//   q   = lane&15 : float4 slot within the 256 B row
// Per wave: 4 h-row gathers + 4 t-row gathers + v (9 dwordx4). Halved
// latency chain, halved VGPR (-> ~2x resident waves), 2x wave count.
// Cross-wave softmax merge (flash-style, exact) + partial-PV add via LDS.
__global__ __launch_bounds__(256)
void kgan_kernel(const float* __restrict__ ent,      // [N_ENT+1, 64]
                 const float* __restrict__ rel,      // [16, 64]
                 const int*   __restrict__ items,    // [256]
                 const int*   __restrict__ mh,
                 const int*   __restrict__ mr,
                 const int*   __restrict__ mt,
                 float*       __restrict__ out)      // [2,256,16,64]
{
    __shared__ float  rel_lds[NREL * DIM];           // 4 KB
    __shared__ float  stats[4][2];                   // {max, sum} per wave
    __shared__ float4 pvbuf[4][16];                  // partial PV per wave

    reinterpret_cast<float4*>(rel_lds)[threadIdx.x] =
        reinterpret_cast<const float4*>(rel)[threadIdx.x];
    __syncthreads();

    const int gtid   = blockIdx.x * blockDim.x + threadIdx.x;
    const int lane   = threadIdx.x & 63;
    const int wgwave = threadIdx.x >> 6;             // 0..3 within block
    const int wave   = gtid >> 6;
    const int trip   = wave >> 1;                    // (hop*B + b)*R + r
    const int hf     = wave & 1;                     // which 16 memories
    const int sub    = lane >> 4;
    const int q      = lane & 15;

    const int b = (trip >> 4) & (BATCH - 1);

    const float4* ent4 = reinterpret_cast<const float4*>(ent);
    const float4* rl4  = reinterpret_cast<const float4*>(rel_lds);

    const int item = items[b];
    const float4 v4 = ent4[(size_t)item * 16 + q];

    // lane-distributed indices for this wave's 16 memories
    const int base = trip * NMEM + hf * 16;
    const int lm   = lane & 15;
    const int vh   = mh[base + lm];
    const int vr   = mr[base + lm];
    const int vt   = mt[base + lm];

    // ---- issue all 8 entity gathers (4 h + 4 t) up front ----
    float4 hb[4], tb[4];
    int ridx[4];
    #pragma unroll
    for (int j = 0; j < 4; ++j) {
        const int hid = __shfl(vh, 4 * j + sub, 64);  // ds_bpermute
        hb[j] = ent4[(size_t)hid * 16 + q];
    }
    #pragma unroll
    for (int j = 0; j < 4; ++j) {
        const int tid = __shfl(vt, 4 * j + sub, 64);
        tb[j] = ent4[(size_t)tid * 16 + q];
    }
    #pragma unroll
    for (int j = 0; j < 4; ++j)
        ridx[j] = __shfl(vr, 4 * j + sub, 64);

    // ---- scores for local memories (4j+sub): dot4 + 16-lane reduce ----
    float sc[4];
    #pragma unroll
    for (int j = 0; j < 4; ++j) {
        const float4 r4 = rl4[ridx[j] * 16 + q];
        const float4 h4 = hb[j];
        float p = h4.x * r4.x * v4.x;
        p = fmaf(h4.y * r4.y, v4.y, p);
        p = fmaf(h4.z * r4.z, v4.z, p);
        p = fmaf(h4.w * r4.w, v4.w, p);
        p += __shfl_xor(p, 8, 64);
        p += __shfl_xor(p, 4, 64);
        p += __shfl_xor(p, 2, 64);
        p += __shfl_xor(p, 1, 64);
        sc[j] = p;
    }

    // ---- wave-local softmax stats over its 16 memories ----
    float mx = fmaxf(fmaxf(sc[0], sc[1]), fmaxf(sc[2], sc[3]));
    mx = fmaxf(mx, __shfl_xor(mx, 16, 64));
    mx = fmaxf(mx, __shfl_xor(mx, 32, 64));

    float sum = 0.f;
    #pragma unroll
    for (int j = 0; j < 4; ++j) {
        sc[j] = __expf(sc[j] - mx);
        sum += sc[j];
    }
    sum += __shfl_xor(sum, 16, 64);
    sum += __shfl_xor(sum, 32, 64);

    if (lane == 0) { stats[wgwave][0] = mx; stats[wgwave][1] = sum; }
    __syncthreads();

    // ---- exact two-block softmax merge with partner wave ----
    const int prt = wgwave ^ 1;
    const float m1 = stats[prt][0], s1 = stats[prt][1];
    const float ms = fmaxf(mx, m1);
    const float f0 = __expf(mx - ms);
    const float tot = sum * f0 + s1 * __expf(m1 - ms);
    const float scale = f0 / tot;       // prob_k = sc[k] * scale

    // ---- partial PV over this wave's 16 memories ----
    float4 acc = make_float4(0.f, 0.f, 0.f, 0.f);
    #pragma unroll
    for (int j = 0; j < 4; ++j) {
        const float p = sc[j] * scale;
        acc.x = fmaf(p, tb[j].x, acc.x);
        acc.y = fmaf(p, tb[j].y, acc.y);
        acc.z = fmaf(p, tb[j].z, acc.z);
        acc.w = fmaf(p, tb[j].w, acc.w);
    }
    acc.x += __shfl_xor(acc.x, 16, 64);
    acc.y += __shfl_xor(acc.y, 16, 64);
    acc.z += __shfl_xor(acc.z, 16, 64);
    acc.w += __shfl_xor(acc.w, 16, 64);
    acc.x += __shfl_xor(acc.x, 32, 64);
    acc.y += __shfl_xor(acc.y, 32, 64);
    acc.z += __shfl_xor(acc.z, 32, 64);
    acc.w += __shfl_xor(acc.w, 32, 64);

    if (sub == 0) pvbuf[wgwave][q] = acc;
    __syncthreads();

    if (hf == 0 && sub == 0) {
        const float4 p2 = pvbuf[wgwave + 1][q];
        acc.x += p2.x; acc.y += p2.y; acc.z += p2.z; acc.w += p2.w;
        reinterpret_cast<float4*>(out)[(size_t)trip * 16 + q] = acc;
    }
}

extern "C" void kernel_launch(void* const* d_in, const int* in_sizes, int n_in,
                              void* d_out, int out_size, void* d_ws, size_t ws_size,
                              hipStream_t stream) {
    const float* ent   = (const float*)d_in[0];
    const float* rel   = (const float*)d_in[1];
    const int*   items = (const int*)d_in[2];
    const int*   mh    = (const int*)d_in[3];
    const int*   mr    = (const int*)d_in[4];
    const int*   mt    = (const int*)d_in[5];
    float* out = (float*)d_out;

    const int total_waves = NHOP * BATCH * NREL * 2;   // 16384
    const int threads = 256;
    const int blocks = total_waves * 64 / threads;     // 4096

    kgan_kernel<<<blocks, threads, 0, stream>>>(ent, rel, items, mh, mr, mt, out);
}